// Round 2
// baseline (289.028 us; speedup 1.0000x reference)
//
#include <hip/hip_runtime.h>
#include <stdint.h>

typedef unsigned short u16;
typedef unsigned int u32;
typedef u16 u16x8 __attribute__((ext_vector_type(8)));
typedef __bf16 bf16x8 __attribute__((ext_vector_type(8)));
typedef float f32x4 __attribute__((ext_vector_type(4)));

#define S_LEN 1374
#define S_PAD 1408
#define PRE_TOK 5
#define HID 768
#define NH 12
#define MPAD 11008

__device__ __forceinline__ u16 f2bf(float f) {
    union { float f; u32 u; } v; v.f = f;
    u32 r = v.u + 0x7fffu + ((v.u >> 16) & 1u);
    return (u16)(r >> 16);
}
__device__ __forceinline__ float bf2f(u16 h) {
    union { u32 u; float f; } v; v.u = ((u32)h) << 16;
    return v.f;
}
__device__ __forceinline__ bf16x8 as_bf(u16x8 v) { bf16x8 r; __builtin_memcpy(&r, &v, 16); return r; }
__device__ __forceinline__ bf16x8 lds_load8(const u16* p) {
    u16x8 t = *(const u16x8*)p;
    return as_bf(t);
}
// async global->LDS, 16B per lane. LDS dest = wave-uniform base + lane*16.
__device__ __forceinline__ void gload16(void* lds, const void* g) {
    unsigned int __attribute__((address_space(1)))* gp =
        (unsigned int __attribute__((address_space(1)))*)(unsigned long long)g;
    unsigned int __attribute__((address_space(3)))* lp =
        (unsigned int __attribute__((address_space(3)))*)(unsigned int)(unsigned long long)lds;
    __builtin_amdgcn_global_load_lds(gp, lp, 16, 0, 0);
}

// ---------------- pack kernels ----------------

__global__ __launch_bounds__(256) void pack_x(const float* __restrict__ X, u16* __restrict__ Xb) {
    size_t i = (size_t)blockIdx.x * 256 + threadIdx.x;
    size_t e = i * 8;
    const size_t TOT = (size_t)10992 * HID;
    u16x8 o = {0,0,0,0,0,0,0,0};
    if (e < TOT) {
        f32x4 a = *(const f32x4*)(X + e);
        f32x4 b = *(const f32x4*)(X + e + 4);
#pragma unroll
        for (int j = 0; j < 4; ++j) { o[j] = f2bf(a[j]); o[4 + j] = f2bf(b[j]); }
    }
    *(u16x8*)(Xb + e) = o;
}

__global__ __launch_bounds__(256) void pack_w(
    const float* __restrict__ Wq, const float* __restrict__ Wk, const float* __restrict__ Wv,
    const float* __restrict__ Wp, const float* __restrict__ bq, const float* __restrict__ bv,
    u16* __restrict__ wqkv, u16* __restrict__ wpb, float* __restrict__ bqkv)
{
    int g = blockIdx.x * 256 + threadIdx.x;
    const int QKV8 = 2304 * HID / 8;   // 221184
    const int P8 = HID * HID / 8;      // 73728
    if (g < QKV8) {
        int e = g * 8;
        int row = e / HID, col = e - row * HID;
        const float* src = (row < 768) ? (Wq + (size_t)row * HID + col)
                         : (row < 1536) ? (Wk + (size_t)(row - 768) * HID + col)
                                        : (Wv + (size_t)(row - 1536) * HID + col);
        u16x8 o;
#pragma unroll
        for (int j = 0; j < 8; ++j) o[j] = f2bf(src[j]);
        *(u16x8*)(wqkv + e) = o;
    } else if (g < QKV8 + P8) {
        int e = (g - QKV8) * 8;
        u16x8 o;
#pragma unroll
        for (int j = 0; j < 8; ++j) o[j] = f2bf(Wp[e + j]);
        *(u16x8*)(wpb + e) = o;
    }
    if (g < 288) {
        int e = g * 8;
#pragma unroll
        for (int j = 0; j < 8; ++j) {
            int c = e + j;
            bqkv[c] = (c < 768) ? bq[c] : (c < 1536 ? 0.f : bv[c - 1536]);
        }
    }
}

// ---------------- GEMM: C[m,n] = sum_k A[m,k]*B[n,k] (+bias[n]) ----------------
// A: [>=row-tiles*128][K] bf16, B: [N][K] bf16. 128x128 tile, BK=64, 4 waves (2x2),
// global_load_lds staging with pre-swizzled source; XOR-swizzled ds_read_b128.

template <int OUTF32>
__global__ __launch_bounds__(256) void gemm_nt(
    const u16* __restrict__ A, const u16* __restrict__ B, const float* __restrict__ bias,
    u16* __restrict__ Yb, float* __restrict__ Yf, int Mstore, int N, int K)
{
    __shared__ u16 As[128 * 64];
    __shared__ u16 Bs[128 * 64];
    int tid = threadIdx.x;
    int w = tid >> 6, l = tid & 63;
    int fr = l & 15, fg = l >> 4;
    int row0 = blockIdx.y * 128;
    int col0 = blockIdx.x * 128;
    int wr = (w >> 1) * 64, wc = (w & 1) * 64;

    f32x4 zero4 = {0.f, 0.f, 0.f, 0.f};
    f32x4 acc[4][4];
#pragma unroll
    for (int m = 0; m < 4; ++m)
#pragma unroll
        for (int n = 0; n < 4; ++n) acc[m][n] = zero4;

    int srow[4], soff[4];
#pragma unroll
    for (int i = 0; i < 4; ++i) {
        int sbyte = (i * 4 + w) * 1024 + l * 16;
        int r = sbyte >> 7;
        int ir = (sbyte & 127) ^ ((r & 7) << 4);
        srow[i] = r; soff[i] = ir >> 1;
    }

    for (int kt = 0; kt < K; kt += 64) {
#pragma unroll
        for (int i = 0; i < 4; ++i) {
            int sb = (i * 4 + w) * 1024;
            gload16((char*)As + sb, A + (size_t)(row0 + srow[i]) * K + kt + soff[i]);
            gload16((char*)Bs + sb, B + (size_t)(col0 + srow[i]) * K + kt + soff[i]);
        }
        __syncthreads();
#pragma unroll
        for (int c = 0; c < 2; ++c) {
            bf16x8 af[4], bfr[4];
#pragma unroll
            for (int m = 0; m < 4; ++m) {
                int r = wr + m * 16 + fr;
                int byte_ = (c * 64 + fg * 16) ^ ((r & 7) << 4);
                af[m] = lds_load8(As + r * 64 + (byte_ >> 1));
            }
#pragma unroll
            for (int n = 0; n < 4; ++n) {
                int r = wc + n * 16 + fr;
                int byte_ = (c * 64 + fg * 16) ^ ((r & 7) << 4);
                bfr[n] = lds_load8(Bs + r * 64 + (byte_ >> 1));
            }
#pragma unroll
            for (int m = 0; m < 4; ++m)
#pragma unroll
                for (int n = 0; n < 4; ++n)
                    acc[m][n] = __builtin_amdgcn_mfma_f32_16x16x32_bf16(af[m], bfr[n], acc[m][n], 0, 0, 0);
        }
        __syncthreads();
    }

#pragma unroll
    for (int m = 0; m < 4; ++m)
#pragma unroll
        for (int n = 0; n < 4; ++n) {
            int gn = col0 + wc + n * 16 + fr;
            float bvv = bias[gn];
#pragma unroll
            for (int j = 0; j < 4; ++j) {
                int gm = row0 + wr + m * 16 + fg * 4 + j;
                float v = acc[m][n][j] + bvv;
                if (OUTF32) {
                    if (gm < Mstore) Yf[(size_t)gm * N + gn] = v;
                } else {
                    Yb[(size_t)gm * N + gn] = f2bf(v);
                }
            }
        }
}

// ---------------- RoPE + head packing ----------------
// Y: [MPAD][2304] bf16 (q|k|v). Outputs: Qh,Kh [96][S_PAD][64] bf16 (Q scaled by 1/8),
// Vt [96][64][S_PAD] bf16. Zero-fills s in [S_LEN, S_PAD).

__global__ __launch_bounds__(256) void rope_pack(
    const u16* __restrict__ Y, const float* __restrict__ SN, const float* __restrict__ CS,
    u16* __restrict__ Qh, u16* __restrict__ Kh, u16* __restrict__ Vt)
{
    int st = blockIdx.x, bh = blockIdx.y;
    int b = bh / NH, h = bh - b * NH;
    int tid = threadIdx.x;
    int sl = tid >> 2, dg = (tid & 3) * 8;
    int s = st * 64 + sl;
    __shared__ u16 vtile[64 * 64];

    float q1[8], q2[8], k1[8], k2[8], v1[8], v2[8];
    if (s < S_LEN) {
        size_t trow = ((size_t)b * S_LEN + s) * 2304 + h * 64;
        u16x8 a;
        a = *(const u16x8*)(Y + trow + dg);
#pragma unroll
        for (int j = 0; j < 8; ++j) q1[j] = bf2f(a[j]);
        a = *(const u16x8*)(Y + trow + 32 + dg);
#pragma unroll
        for (int j = 0; j < 8; ++j) q2[j] = bf2f(a[j]);
        a = *(const u16x8*)(Y + trow + 768 + dg);
#pragma unroll
        for (int j = 0; j < 8; ++j) k1[j] = bf2f(a[j]);
        a = *(const u16x8*)(Y + trow + 800 + dg);
#pragma unroll
        for (int j = 0; j < 8; ++j) k2[j] = bf2f(a[j]);
        a = *(const u16x8*)(Y + trow + 1536 + dg);
#pragma unroll
        for (int j = 0; j < 8; ++j) v1[j] = bf2f(a[j]);
        a = *(const u16x8*)(Y + trow + 1568 + dg);
#pragma unroll
        for (int j = 0; j < 8; ++j) v2[j] = bf2f(a[j]);
        if (s >= PRE_TOK) {
            size_t r = (size_t)(s - PRE_TOK) * 64;
#pragma unroll
            for (int j = 0; j < 8; ++j) {
                float c1 = CS[r + dg + j], c2 = CS[r + 32 + dg + j];
                float s1 = SN[r + dg + j], s2 = SN[r + 32 + dg + j];
                float a1 = q1[j] * c1 - q2[j] * s1;
                float a2 = q2[j] * c2 + q1[j] * s2;
                q1[j] = a1; q2[j] = a2;
                a1 = k1[j] * c1 - k2[j] * s1;
                a2 = k2[j] * c2 + k1[j] * s2;
                k1[j] = a1; k2[j] = a2;
            }
        }
#pragma unroll
        for (int j = 0; j < 8; ++j) { q1[j] *= 0.125f; q2[j] *= 0.125f; }
    } else {
#pragma unroll
        for (int j = 0; j < 8; ++j) { q1[j]=q2[j]=k1[j]=k2[j]=v1[j]=v2[j]=0.f; }
    }

    size_t ob = ((size_t)bh * S_PAD + s) * 64;
    u16x8 o;
#pragma unroll
    for (int j = 0; j < 8; ++j) o[j] = f2bf(q1[j]);
    *(u16x8*)(Qh + ob + dg) = o;
#pragma unroll
    for (int j = 0; j < 8; ++j) o[j] = f2bf(q2[j]);
    *(u16x8*)(Qh + ob + 32 + dg) = o;
#pragma unroll
    for (int j = 0; j < 8; ++j) o[j] = f2bf(k1[j]);
    *(u16x8*)(Kh + ob + dg) = o;
#pragma unroll
    for (int j = 0; j < 8; ++j) o[j] = f2bf(k2[j]);
    *(u16x8*)(Kh + ob + 32 + dg) = o;
#pragma unroll
    for (int j = 0; j < 8; ++j) {
        vtile[(dg + j) * 64 + sl] = f2bf(v1[j]);
        vtile[(32 + dg + j) * 64 + sl] = f2bf(v2[j]);
    }
    __syncthreads();
    // Read-out: each thread emits TWO u16x8 chunks so the full 64x64 tile is
    // covered (256 threads x 16 elems = 4096).  [R1 fix: previous version
    // only wrote seq offsets 0..31, leaving half of Vt as poison.]
    int d = tid >> 2, so = (tid & 3) * 8;
    u16x8 ov0 = *(const u16x8*)(vtile + d * 64 + so);
    u16x8 ov1 = *(const u16x8*)(vtile + d * 64 + so + 32);
    size_t vrow = ((size_t)bh * 64 + d) * S_PAD + st * 64;
    *(u16x8*)(Vt + vrow + so) = ov0;
    *(u16x8*)(Vt + vrow + so + 32) = ov1;
}

// ---------------- flash attention ----------------
// grid (22 q-tiles, 96 heads). 4 waves; wave w owns q rows [q0+16w, q0+16w+16).
// Q pre-scaled by 1/8. Online softmax fp32, P staged in swizzled per-wave LDS.

__global__ __launch_bounds__(256) void flash(
    const u16* __restrict__ Qh, const u16* __restrict__ Kh, const u16* __restrict__ Vt,
    u16* __restrict__ ctxO)
{
    int qt = blockIdx.x, bh = blockIdx.y;
    int b = bh / NH, h = bh - b * NH;
    int q0 = qt * 64;
    int tid = threadIdx.x, w = tid >> 6, l = tid & 63;
    int fr = l & 15, fg = l >> 4;

    __shared__ u16 Ks[64 * 64];
    __shared__ u16 Vs[64 * 64];
    __shared__ u16 Ps[4 * 1024];

    const u16* Qb = Qh + (size_t)bh * S_PAD * 64;
    const u16* Kb = Kh + (size_t)bh * S_PAD * 64;
    const u16* Vb = Vt + (size_t)bh * 64 * S_PAD;

    bf16x8 qf[2];
    {
        int qrow = q0 + w * 16 + fr;
#pragma unroll
        for (int c = 0; c < 2; ++c)
            qf[c] = as_bf(*(const u16x8*)(Qb + (size_t)qrow * 64 + c * 32 + fg * 8));
    }

    f32x4 zero4 = {0.f, 0.f, 0.f, 0.f};
    f32x4 octx[4] = {zero4, zero4, zero4, zero4};
    float mrow[4] = {-3e38f, -3e38f, -3e38f, -3e38f};
    float lrow[4] = {0.f, 0.f, 0.f, 0.f};

    int srow[2], soff[2];
#pragma unroll
    for (int i = 0; i < 2; ++i) {
        int sbyte = (i * 4 + w) * 1024 + l * 16;
        int r = sbyte >> 7;
        int ir = (sbyte & 127) ^ ((r & 7) << 4);
        srow[i] = r; soff[i] = ir >> 1;
    }

    for (int kt = 0; kt < 22; ++kt) {
        int k0 = kt * 64;
#pragma unroll
        for (int i = 0; i < 2; ++i) {
            int sb = (i * 4 + w) * 1024;
            gload16((char*)Ks + sb, Kb + (size_t)(k0 + srow[i]) * 64 + soff[i]);
            gload16((char*)Vs + sb, Vb + (size_t)srow[i] * S_PAD + k0 + soff[i]);
        }
        __syncthreads();

        f32x4 sf[4];
#pragma unroll
        for (int n = 0; n < 4; ++n) {
            f32x4 acc = zero4;
#pragma unroll
            for (int c = 0; c < 2; ++c) {
                int r = n * 16 + fr;
                int byte_ = (c * 64 + fg * 16) ^ ((r & 7) << 4);
                bf16x8 kf = lds_load8(Ks + r * 64 + (byte_ >> 1));
                acc = __builtin_amdgcn_mfma_f32_16x16x32_bf16(qf[c], kf, acc, 0, 0, 0);
            }
            sf[n] = acc;
        }
        if (k0 + 64 > S_LEN) {
#pragma unroll
            for (int n = 0; n < 4; ++n)
                if (k0 + n * 16 + fr >= S_LEN) {
                    sf[n][0] = -1e30f; sf[n][1] = -1e30f; sf[n][2] = -1e30f; sf[n][3] = -1e30f;
                }
        }
#pragma unroll
        for (int j = 0; j < 4; ++j) {
            float mx = fmaxf(fmaxf(sf[0][j], sf[1][j]), fmaxf(sf[2][j], sf[3][j]));
#pragma unroll
            for (int d = 1; d < 16; d <<= 1) mx = fmaxf(mx, __shfl_xor(mx, d));
            float mnew = fmaxf(mrow[j], mx);
            float corr = __expf(mrow[j] - mnew);
            mrow[j] = mnew;
            float ps = 0.f;
#pragma unroll
            for (int n = 0; n < 4; ++n) {
                float p = __expf(sf[n][j] - mnew);
                sf[n][j] = p; ps += p;
            }
#pragma unroll
            for (int d = 1; d < 16; d <<= 1) ps += __shfl_xor(ps, d);
            lrow[j] = lrow[j] * corr + ps;
            octx[0][j] *= corr; octx[1][j] *= corr; octx[2][j] *= corr; octx[3][j] *= corr;
        }
        u16* Pw = Ps + w * 1024;
#pragma unroll
        for (int n = 0; n < 4; ++n)
#pragma unroll
            for (int j = 0; j < 4; ++j) {
                int q = fg * 4 + j, key = n * 16 + fr;
                int byte_ = (key * 2) ^ ((q & 7) << 4);
                Pw[q * 64 + (byte_ >> 1)] = f2bf(sf[n][j]);
            }
        asm volatile("s_waitcnt lgkmcnt(0)" ::: "memory");
        __builtin_amdgcn_sched_barrier(0);
#pragma unroll
        for (int nd = 0; nd < 4; ++nd) {
#pragma unroll
            for (int c = 0; c < 2; ++c) {
                int pbyte = (c * 64 + fg * 16) ^ ((fr & 7) << 4);
                bf16x8 pf = lds_load8(Pw + fr * 64 + (pbyte >> 1));
                int vr = nd * 16 + fr;
                int vbyte = (c * 64 + fg * 16) ^ ((vr & 7) << 4);
                bf16x8 vf = lds_load8(Vs + vr * 64 + (vbyte >> 1));
                octx[nd] = __builtin_amdgcn_mfma_f32_16x16x32_bf16(pf, vf, octx[nd], 0, 0, 0);
            }
        }
        __syncthreads();
    }

#pragma unroll
    for (int j = 0; j < 4; ++j) {
        int q = q0 + w * 16 + fg * 4 + j;
        if (q < S_LEN) {
            float inv = 1.f / lrow[j];
            size_t rowb = ((size_t)b * S_LEN + q) * HID + h * 64;
#pragma unroll
            for (int nd = 0; nd < 4; ++nd)
                ctxO[rowb + nd * 16 + fr] = f2bf(octx[nd][j] * inv);
        }
    }
}

// ---------------- launch ----------------

extern "C" void kernel_launch(void* const* d_in, const int* in_sizes, int n_in,
                              void* d_out, int out_size, void* d_ws, size_t ws_size,
                              hipStream_t stream) {
    (void)in_sizes; (void)n_in; (void)out_size; (void)ws_size;
    const float* X  = (const float*)d_in[0];
    const float* SN = (const float*)d_in[1];
    const float* CS = (const float*)d_in[2];
    const float* Wq = (const float*)d_in[3];
    const float* bq = (const float*)d_in[4];
    const float* Wk = (const float*)d_in[5];
    const float* Wv = (const float*)d_in[6];
    const float* bv = (const float*)d_in[7];
    const float* Wp = (const float*)d_in[8];
    const float* bp = (const float*)d_in[9];
    float* OUT = (float*)d_out;
    char* ws = (char*)d_ws;

    u16*   xb   = (u16*)(ws);                    // [11008][768] bf16, 16,908,288 B; later reused as ctx
    u16*   wqkv = (u16*)(ws + 16908288);         // [2304][768] bf16
    u16*   wpb  = (u16*)(ws + 20447232);         // [768][768] bf16
    float* bqkv = (float*)(ws + 21626880);       // [2304] f32
    u16*   Y    = (u16*)(ws + 21636096);         // [11008][2304] bf16
    u16*   Qh   = (u16*)(ws + 72360960);         // [96][1408][64] bf16
    u16*   Kh   = (u16*)(ws + 89662464);
    u16*   Vt   = (u16*)(ws + 106963968);        // [96][64][1408] bf16; end 124,265,472
    u16*   ctx  = xb;

    pack_x<<<4128, 256, 0, stream>>>(X, xb);
    pack_w<<<1152, 256, 0, stream>>>(Wq, Wk, Wv, Wp, bq, bv, wqkv, wpb, bqkv);
    gemm_nt<0><<<dim3(18, 86), 256, 0, stream>>>(xb, wqkv, bqkv, Y, nullptr, MPAD, 2304, 768);
    rope_pack<<<dim3(22, 96), 256, 0, stream>>>(Y, SN, CS, Qh, Kh, Vt);
    flash<<<dim3(22, 96), 256, 0, stream>>>(Qh, Kh, Vt, ctx);
    gemm_nt<1><<<dim3(6, 86), 256, 0, stream>>>(ctx, wpb, bp, nullptr, OUT, 10992, 768, 768);
}

// Round 4
// 231.950 us; speedup vs baseline: 1.2461x; 1.2461x over previous
//
#include <hip/hip_runtime.h>
#include <stdint.h>

typedef unsigned short u16;
typedef unsigned int u32;
typedef u16 u16x8 __attribute__((ext_vector_type(8)));
typedef __bf16 bf16x8 __attribute__((ext_vector_type(8)));
typedef float f32x4 __attribute__((ext_vector_type(4)));

#define S_LEN 1374
#define S_PAD 1408
#define PRE_TOK 5
#define HID 768
#define NH 12
#define MPAD 11008

__device__ __forceinline__ u16 f2bf(float f) {
    union { float f; u32 u; } v; v.f = f;
    u32 r = v.u + 0x7fffu + ((v.u >> 16) & 1u);
    return (u16)(r >> 16);
}
__device__ __forceinline__ float bf2f(u16 h) {
    union { u32 u; float f; } v; v.u = ((u32)h) << 16;
    return v.f;
}
__device__ __forceinline__ bf16x8 as_bf(u16x8 v) { bf16x8 r; __builtin_memcpy(&r, &v, 16); return r; }
__device__ __forceinline__ bf16x8 lds_load8(const u16* p) {
    u16x8 t = *(const u16x8*)p;
    return as_bf(t);
}
__device__ __forceinline__ u32 cvtpk_bf16(float lo, float hi) {
    u32 r;
    asm("v_cvt_pk_bf16_f32 %0, %1, %2" : "=v"(r) : "v"(lo), "v"(hi));
    return r;
}
// async global->LDS, 16B per lane. LDS dest = wave-uniform base + lane*16.
__device__ __forceinline__ void gload16(void* lds, const void* g) {
    unsigned int __attribute__((address_space(1)))* gp =
        (unsigned int __attribute__((address_space(1)))*)(unsigned long long)g;
    unsigned int __attribute__((address_space(3)))* lp =
        (unsigned int __attribute__((address_space(3)))*)(unsigned int)(unsigned long long)lds;
    __builtin_amdgcn_global_load_lds(gp, lp, 16, 0, 0);
}

// ---------------- pack kernels ----------------

__global__ __launch_bounds__(256) void pack_x(const float* __restrict__ X, u16* __restrict__ Xb) {
    size_t i = (size_t)blockIdx.x * 256 + threadIdx.x;
    size_t e = i * 8;
    const size_t TOT = (size_t)10992 * HID;
    u16x8 o = {0,0,0,0,0,0,0,0};
    if (e < TOT) {
        f32x4 a = *(const f32x4*)(X + e);
        f32x4 b = *(const f32x4*)(X + e + 4);
#pragma unroll
        for (int j = 0; j < 4; ++j) { o[j] = f2bf(a[j]); o[4 + j] = f2bf(b[j]); }
    }
    *(u16x8*)(Xb + e) = o;
}

__global__ __launch_bounds__(256) void pack_w(
    const float* __restrict__ Wq, const float* __restrict__ Wk, const float* __restrict__ Wv,
    const float* __restrict__ Wp, const float* __restrict__ bq, const float* __restrict__ bv,
    u16* __restrict__ wqkv, u16* __restrict__ wpb, float* __restrict__ bqkv)
{
    int g = blockIdx.x * 256 + threadIdx.x;
    const int QKV8 = 2304 * HID / 8;   // 221184
    const int P8 = HID * HID / 8;      // 73728
    if (g < QKV8) {
        int e = g * 8;
        int row = e / HID, col = e - row * HID;
        const float* src = (row < 768) ? (Wq + (size_t)row * HID + col)
                         : (row < 1536) ? (Wk + (size_t)(row - 768) * HID + col)
                                        : (Wv + (size_t)(row - 1536) * HID + col);
        u16x8 o;
#pragma unroll
        for (int j = 0; j < 8; ++j) o[j] = f2bf(src[j]);
        *(u16x8*)(wqkv + e) = o;
    } else if (g < QKV8 + P8) {
        int e = (g - QKV8) * 8;
        u16x8 o;
#pragma unroll
        for (int j = 0; j < 8; ++j) o[j] = f2bf(Wp[e + j]);
        *(u16x8*)(wpb + e) = o;
    }
    if (g < 288) {
        int e = g * 8;
#pragma unroll
        for (int j = 0; j < 8; ++j) {
            int c = e + j;
            bqkv[c] = (c < 768) ? bq[c] : (c < 1536 ? 0.f : bv[c - 1536]);
        }
    }
}

// ---------------- GEMM: C[m,n] = sum_k A[m,k]*B[n,k] (+bias[n]) ----------------

template <int OUTF32>
__global__ __launch_bounds__(256) void gemm_nt(
    const u16* __restrict__ A, const u16* __restrict__ B, const float* __restrict__ bias,
    u16* __restrict__ Yb, float* __restrict__ Yf, int Mstore, int N, int K)
{
    __shared__ u16 As[128 * 64];
    __shared__ u16 Bs[128 * 64];
    int tid = threadIdx.x;
    int w = tid >> 6, l = tid & 63;
    int fr = l & 15, fg = l >> 4;
    int row0 = blockIdx.y * 128;
    int col0 = blockIdx.x * 128;
    int wr = (w >> 1) * 64, wc = (w & 1) * 64;

    f32x4 zero4 = {0.f, 0.f, 0.f, 0.f};
    f32x4 acc[4][4];
#pragma unroll
    for (int m = 0; m < 4; ++m)
#pragma unroll
        for (int n = 0; n < 4; ++n) acc[m][n] = zero4;

    int srow[4], soff[4];
#pragma unroll
    for (int i = 0; i < 4; ++i) {
        int sbyte = (i * 4 + w) * 1024 + l * 16;
        int r = sbyte >> 7;
        int ir = (sbyte & 127) ^ ((r & 7) << 4);
        srow[i] = r; soff[i] = ir >> 1;
    }

    for (int kt = 0; kt < K; kt += 64) {
#pragma unroll
        for (int i = 0; i < 4; ++i) {
            int sb = (i * 4 + w) * 1024;
            gload16((char*)As + sb, A + (size_t)(row0 + srow[i]) * K + kt + soff[i]);
            gload16((char*)Bs + sb, B + (size_t)(col0 + srow[i]) * K + kt + soff[i]);
        }
        __syncthreads();
#pragma unroll
        for (int c = 0; c < 2; ++c) {
            bf16x8 af[4], bfr[4];
#pragma unroll
            for (int m = 0; m < 4; ++m) {
                int r = wr + m * 16 + fr;
                int byte_ = (c * 64 + fg * 16) ^ ((r & 7) << 4);
                af[m] = lds_load8(As + r * 64 + (byte_ >> 1));
            }
#pragma unroll
            for (int n = 0; n < 4; ++n) {
                int r = wc + n * 16 + fr;
                int byte_ = (c * 64 + fg * 16) ^ ((r & 7) << 4);
                bfr[n] = lds_load8(Bs + r * 64 + (byte_ >> 1));
            }
#pragma unroll
            for (int m = 0; m < 4; ++m)
#pragma unroll
                for (int n = 0; n < 4; ++n)
                    acc[m][n] = __builtin_amdgcn_mfma_f32_16x16x32_bf16(af[m], bfr[n], acc[m][n], 0, 0, 0);
        }
        __syncthreads();
    }

#pragma unroll
    for (int m = 0; m < 4; ++m)
#pragma unroll
        for (int n = 0; n < 4; ++n) {
            int gn = col0 + wc + n * 16 + fr;
            float bvv = bias[gn];
#pragma unroll
            for (int j = 0; j < 4; ++j) {
                int gm = row0 + wr + m * 16 + fg * 4 + j;
                float v = acc[m][n][j] + bvv;
                if (OUTF32) {
                    if (gm < Mstore) Yf[(size_t)gm * N + gn] = v;
                } else {
                    Yb[(size_t)gm * N + gn] = f2bf(v);
                }
            }
        }
}

// ---------------- RoPE + head packing ----------------
// Q pre-scaled by 1/8 * log2(e)  (flash works in exp2 domain).

__global__ __launch_bounds__(256) void rope_pack(
    const u16* __restrict__ Y, const float* __restrict__ SN, const float* __restrict__ CS,
    u16* __restrict__ Qh, u16* __restrict__ Kh, u16* __restrict__ Vt)
{
    int st = blockIdx.x, bh = blockIdx.y;
    int b = bh / NH, h = bh - b * NH;
    int tid = threadIdx.x;
    int sl = tid >> 2, dg = (tid & 3) * 8;
    int s = st * 64 + sl;
    __shared__ u16 vtile[64 * 64];
    const float QSCALE = 0.125f * 1.44269504088896f;

    float q1[8], q2[8], k1[8], k2[8], v1[8], v2[8];
    if (s < S_LEN) {
        size_t trow = ((size_t)b * S_LEN + s) * 2304 + h * 64;
        u16x8 a;
        a = *(const u16x8*)(Y + trow + dg);
#pragma unroll
        for (int j = 0; j < 8; ++j) q1[j] = bf2f(a[j]);
        a = *(const u16x8*)(Y + trow + 32 + dg);
#pragma unroll
        for (int j = 0; j < 8; ++j) q2[j] = bf2f(a[j]);
        a = *(const u16x8*)(Y + trow + 768 + dg);
#pragma unroll
        for (int j = 0; j < 8; ++j) k1[j] = bf2f(a[j]);
        a = *(const u16x8*)(Y + trow + 800 + dg);
#pragma unroll
        for (int j = 0; j < 8; ++j) k2[j] = bf2f(a[j]);
        a = *(const u16x8*)(Y + trow + 1536 + dg);
#pragma unroll
        for (int j = 0; j < 8; ++j) v1[j] = bf2f(a[j]);
        a = *(const u16x8*)(Y + trow + 1568 + dg);
#pragma unroll
        for (int j = 0; j < 8; ++j) v2[j] = bf2f(a[j]);
        if (s >= PRE_TOK) {
            size_t r = (size_t)(s - PRE_TOK) * 64;
#pragma unroll
            for (int j = 0; j < 8; ++j) {
                float c1 = CS[r + dg + j], c2 = CS[r + 32 + dg + j];
                float s1 = SN[r + dg + j], s2 = SN[r + 32 + dg + j];
                float a1 = q1[j] * c1 - q2[j] * s1;
                float a2 = q2[j] * c2 + q1[j] * s2;
                q1[j] = a1; q2[j] = a2;
                a1 = k1[j] * c1 - k2[j] * s1;
                a2 = k2[j] * c2 + k1[j] * s2;
                k1[j] = a1; k2[j] = a2;
            }
        }
#pragma unroll
        for (int j = 0; j < 8; ++j) { q1[j] *= QSCALE; q2[j] *= QSCALE; }
    } else {
#pragma unroll
        for (int j = 0; j < 8; ++j) { q1[j]=q2[j]=k1[j]=k2[j]=v1[j]=v2[j]=0.f; }
    }

    size_t ob = ((size_t)bh * S_PAD + s) * 64;
    u16x8 o;
#pragma unroll
    for (int j = 0; j < 8; ++j) o[j] = f2bf(q1[j]);
    *(u16x8*)(Qh + ob + dg) = o;
#pragma unroll
    for (int j = 0; j < 8; ++j) o[j] = f2bf(q2[j]);
    *(u16x8*)(Qh + ob + 32 + dg) = o;
#pragma unroll
    for (int j = 0; j < 8; ++j) o[j] = f2bf(k1[j]);
    *(u16x8*)(Kh + ob + dg) = o;
#pragma unroll
    for (int j = 0; j < 8; ++j) o[j] = f2bf(k2[j]);
    *(u16x8*)(Kh + ob + 32 + dg) = o;
#pragma unroll
    for (int j = 0; j < 8; ++j) {
        vtile[(dg + j) * 64 + sl] = f2bf(v1[j]);
        vtile[(32 + dg + j) * 64 + sl] = f2bf(v2[j]);
    }
    __syncthreads();
    int d = tid >> 2, so = (tid & 3) * 8;
    u16x8 ov0 = *(const u16x8*)(vtile + d * 64 + so);
    u16x8 ov1 = *(const u16x8*)(vtile + d * 64 + so + 32);
    size_t vrow = ((size_t)bh * 64 + d) * S_PAD + st * 64;
    *(u16x8*)(Vt + vrow + so) = ov0;
    *(u16x8*)(Vt + vrow + so + 32) = ov1;
}

// ---------------- flash attention (swapped QK^T, in-register P) ----------------
// Ks row r holds global key k0 + g(r); g = bit-permutation such that lane
// (fr,fg)'s 16 scores are keys {32c + 8*fg + t} — the exact 16x16x32 PV
// A-fragment. Softmax per-lane (q=fr) with 2 shuffles; P packed via cvt_pk.
//
// [R3 fix] Staging loads for tile kt+1 stay in flight across the loop
// back-edge barrier. The compiler's automatic vmcnt drain at __syncthreads
// is only verified for same-block stage->barrier patterns (m97); crossing
// the back-edge needs an EXPLICIT drain (as all verified deep-pipeline
// templates do). Without it: races -> nondeterministic replays.

__global__ __launch_bounds__(256) void flash(
    const u16* __restrict__ Qh, const u16* __restrict__ Kh, const u16* __restrict__ Vt,
    u16* __restrict__ ctxO)
{
    int qt = blockIdx.x, bh = blockIdx.y;
    int b = bh / NH, h = bh - b * NH;
    int q0 = qt * 64;
    int tid = threadIdx.x, w = tid >> 6, l = tid & 63;
    int fr = l & 15, fg = l >> 4;

    __shared__ u16 Ks[2][64 * 64];
    __shared__ u16 Vs[2][64 * 64];

    const u16* Qb = Qh + (size_t)bh * S_PAD * 64;
    const u16* Kb = Kh + (size_t)bh * S_PAD * 64;
    const u16* Vb = Vt + (size_t)bh * 64 * S_PAD;

    bf16x8 qf[2];
    {
        int qrow = q0 + w * 16 + fr;
#pragma unroll
        for (int c = 0; c < 2; ++c)
            qf[c] = as_bf(*(const u16x8*)(Qb + (size_t)qrow * 64 + c * 32 + fg * 8));
    }

    f32x4 zero4 = {0.f, 0.f, 0.f, 0.f};
    f32x4 octx[4] = {zero4, zero4, zero4, zero4};
    float mrow = -3e38f, lrow = 0.f;

    int srowK[2], srowV[2], soff[2];
#pragma unroll
    for (int i = 0; i < 2; ++i) {
        int sbyte = (i * 4 + w) * 1024 + l * 16;
        int r = sbyte >> 7;
        int ir = (sbyte & 127) ^ ((r & 7) << 4);
        soff[i] = ir >> 1;
        srowV[i] = r;
        // g(r): key permutation so fragment reads yield PV-ready key order
        srowK[i] = (r & 32) | (((r >> 4) & 1) << 2) | (((r >> 2) & 3) << 3) | (r & 3);
    }

    auto STAGE = [&](int buf, int kt) {
        int k0 = kt * 64;
#pragma unroll
        for (int i = 0; i < 2; ++i) {
            int sb = (i * 4 + w) * 1024;
            gload16((char*)Ks[buf] + sb, Kb + (size_t)(k0 + srowK[i]) * 64 + soff[i]);
            gload16((char*)Vs[buf] + sb, Vb + (size_t)srowV[i] * S_PAD + k0 + soff[i]);
        }
    };

    STAGE(0, 0);
    int cur = 0;
    for (int kt = 0; kt < 22; ++kt) {
        int k0 = kt * 64;
        // Explicit drain: in-flight stage loads (issued last iteration, cross
        // the back-edge) and all LDS reads must complete before the rendezvous.
        asm volatile("s_waitcnt vmcnt(0) lgkmcnt(0)" ::: "memory");
        __syncthreads();               // buf[cur] fully staged for all waves
        if (kt + 1 < 22) STAGE(cur ^ 1, kt + 1);

        const u16* Kc = Ks[cur];
        const u16* Vc = Vs[cur];

        // QK^T (swapped): sf[n][j] = S[key = k0+32(n>>1)+8fg+4(n&1)+j][q = fr]
        f32x4 sf[4];
        __builtin_amdgcn_s_setprio(1);
#pragma unroll
        for (int n = 0; n < 4; ++n) {
            f32x4 acc = zero4;
#pragma unroll
            for (int c = 0; c < 2; ++c) {
                int r = n * 16 + fr;
                int byte_ = (c * 64 + fg * 16) ^ ((r & 7) << 4);
                bf16x8 kf = lds_load8(Kc + r * 64 + (byte_ >> 1));
                acc = __builtin_amdgcn_mfma_f32_16x16x32_bf16(kf, qf[c], acc, 0, 0, 0);
            }
            sf[n] = acc;
        }
        __builtin_amdgcn_s_setprio(0);

        if (k0 + 64 > S_LEN) {
#pragma unroll
            for (int n = 0; n < 4; ++n)
#pragma unroll
                for (int j = 0; j < 4; ++j) {
                    int key = k0 + 32 * (n >> 1) + 8 * fg + 4 * (n & 1) + j;
                    if (key >= S_LEN) sf[n][j] = -1e30f;
                }
        }

        // per-lane softmax over 16 scores (q = fr), reduce across fg copies
        float pmax = sf[0][0];
#pragma unroll
        for (int n = 0; n < 4; ++n)
#pragma unroll
            for (int j = 0; j < 4; ++j) pmax = fmaxf(pmax, sf[n][j]);
        pmax = fmaxf(pmax, __shfl_xor(pmax, 16));
        pmax = fmaxf(pmax, __shfl_xor(pmax, 32));

        if (__any(pmax > mrow + 8.f)) {          // defer-max (T13), log2 domain
            float mnew = fmaxf(mrow, pmax);
            float corr = exp2f(mrow - mnew);
            mrow = mnew;
            lrow *= corr;
            float cj[4];
#pragma unroll
            for (int j = 0; j < 4; ++j) cj[j] = __shfl(corr, fg * 4 + j, 16);
#pragma unroll
            for (int nd = 0; nd < 4; ++nd)
#pragma unroll
                for (int j = 0; j < 4; ++j) octx[nd][j] *= cj[j];
        }

        float psum = 0.f;
#pragma unroll
        for (int n = 0; n < 4; ++n)
#pragma unroll
            for (int j = 0; j < 4; ++j) {
                float p = exp2f(sf[n][j] - mrow);
                sf[n][j] = p; psum += p;
            }
        psum += __shfl_xor(psum, 16);
        psum += __shfl_xor(psum, 32);
        lrow += psum;

        // pack P into PV A-fragments: pa[c][t] = P[q=fr][32c + 8fg + t]
        union PA { u32 w2[4]; bf16x8 v; } pa[2];
#pragma unroll
        for (int c = 0; c < 2; ++c) {
            pa[c].w2[0] = cvtpk_bf16(sf[2 * c][0], sf[2 * c][1]);
            pa[c].w2[1] = cvtpk_bf16(sf[2 * c][2], sf[2 * c][3]);
            pa[c].w2[2] = cvtpk_bf16(sf[2 * c + 1][0], sf[2 * c + 1][1]);
            pa[c].w2[3] = cvtpk_bf16(sf[2 * c + 1][2], sf[2 * c + 1][3]);
        }

        __builtin_amdgcn_s_setprio(1);
#pragma unroll
        for (int nd = 0; nd < 4; ++nd) {
#pragma unroll
            for (int c = 0; c < 2; ++c) {
                int vr = nd * 16 + fr;
                int vbyte = (c * 64 + fg * 16) ^ ((vr & 7) << 4);
                bf16x8 vf = lds_load8(Vc + vr * 64 + (vbyte >> 1));
                octx[nd] = __builtin_amdgcn_mfma_f32_16x16x32_bf16(pa[c].v, vf, octx[nd], 0, 0, 0);
            }
        }
        __builtin_amdgcn_s_setprio(0);
        cur ^= 1;
    }

    float linv = 1.f / lrow;
    float lj[4];
#pragma unroll
    for (int j = 0; j < 4; ++j) lj[j] = __shfl(linv, fg * 4 + j, 16);
#pragma unroll
    for (int j = 0; j < 4; ++j) {
        int q = q0 + w * 16 + fg * 4 + j;
        if (q < S_LEN) {
            size_t rowb = ((size_t)b * S_LEN + q) * HID + h * 64;
#pragma unroll
            for (int nd = 0; nd < 4; ++nd)
                ctxO[rowb + nd * 16 + fr] = f2bf(octx[nd][j] * lj[j]);
        }
    }
}

// ---------------- launch ----------------

extern "C" void kernel_launch(void* const* d_in, const int* in_sizes, int n_in,
                              void* d_out, int out_size, void* d_ws, size_t ws_size,
                              hipStream_t stream) {
    (void)in_sizes; (void)n_in; (void)out_size; (void)ws_size;
    const float* X  = (const float*)d_in[0];
    const float* SN = (const float*)d_in[1];
    const float* CS = (const float*)d_in[2];
    const float* Wq = (const float*)d_in[3];
    const float* bq = (const float*)d_in[4];
    const float* Wk = (const float*)d_in[5];
    const float* Wv = (const float*)d_in[6];
    const float* bv = (const float*)d_in[7];
    const float* Wp = (const float*)d_in[8];
    const float* bp = (const float*)d_in[9];
    float* OUT = (float*)d_out;
    char* ws = (char*)d_ws;

    u16*   xb   = (u16*)(ws);                    // [11008][768] bf16; later reused as ctx
    u16*   wqkv = (u16*)(ws + 16908288);         // [2304][768] bf16
    u16*   wpb  = (u16*)(ws + 20447232);         // [768][768] bf16
    float* bqkv = (float*)(ws + 21626880);       // [2304] f32
    u16*   Y    = (u16*)(ws + 21636096);         // [11008][2304] bf16
    u16*   Qh   = (u16*)(ws + 72360960);         // [96][1408][64] bf16
    u16*   Kh   = (u16*)(ws + 89662464);
    u16*   Vt   = (u16*)(ws + 106963968);        // [96][64][1408] bf16
    u16*   ctx  = xb;

    pack_x<<<4128, 256, 0, stream>>>(X, xb);
    pack_w<<<1152, 256, 0, stream>>>(Wq, Wk, Wv, Wp, bq, bv, wqkv, wpb, bqkv);
    gemm_nt<0><<<dim3(18, 86), 256, 0, stream>>>(xb, wqkv, bqkv, Y, nullptr, MPAD, 2304, 768);
    rope_pack<<<dim3(22, 96), 256, 0, stream>>>(Y, SN, CS, Qh, Kh, Vt);
    flash<<<dim3(22, 96), 256, 0, stream>>>(Qh, Kh, Vt, ctx);
    gemm_nt<1><<<dim3(6, 86), 256, 0, stream>>>(ctx, wpb, bp, nullptr, OUT, 10992, 768, 768);
}